// Round 8
// baseline (560.120 us; speedup 1.0000x reference)
//
#include <hip/hip_runtime.h>

#define EPS 1e-5f

typedef float v2f __attribute__((ext_vector_type(2)));

__device__ __forceinline__ v2f splat2(float s){ v2f r; r.x = s; r.y = s; return r; }
__device__ __forceinline__ v2f pkfma(v2f a, v2f b, v2f c){ return __builtin_elementwise_fma(a, b, c); }
__device__ __forceinline__ v2f pkmax(v2f a, v2f b){ return __builtin_elementwise_max(a, b); }

__device__ __forceinline__ unsigned absbits(float x){
    return __float_as_uint(x) & 0x7fffffffu;
}

// ---------------------------------------------------------------------------
// Supermask: keep top-half of |scores| by stable ascending rank (argsort of
// argsort). Exact radix-select over abs-bit patterns + stable tie-break.
// Writes masked weights TRANSPOSED: out[k*LD + o] for o in [0,N/K), k in [0,K).
// One block (256 threads) per tensor.
// ---------------------------------------------------------------------------
template<int N, int J, int K, int LD>
__device__ void mask_one(const float* __restrict__ s, const float* __restrict__ w,
                         float* __restrict__ out)
{
    __shared__ unsigned hist[256];
    __shared__ unsigned sh_pref, sh_want;
    const int tid = threadIdx.x;
    if (tid == 0){ sh_pref = 0u; sh_want = (unsigned)J; }
    __syncthreads();
    #pragma unroll
    for (int r = 0; r < 4; ++r){
        const int shift = 24 - 8*r;
        hist[tid] = 0u;
        __syncthreads();
        const unsigned pref = sh_pref;
        for (int i = tid; i < N; i += 256){
            unsigned u = absbits(s[i]);
            bool match = (r == 0) || ((u >> (shift + 8)) == pref);
            if (match) atomicAdd(&hist[(u >> shift) & 0xFFu], 1u);
        }
        __syncthreads();
        if (tid == 0){
            unsigned want = sh_want, cum = 0u; int b = 0;
            for (; b < 256; ++b){ unsigned h = hist[b]; if (cum + h > want) break; cum += h; }
            sh_want = want - cum;
            sh_pref = (pref << 8) | (unsigned)b;
        }
        __syncthreads();
    }
    const unsigned tb  = sh_pref;   // abs-bits of element at sorted position J
    const unsigned rem = sh_want;   // #ties (lowest index first) to also drop
    for (int i = tid; i < N; i += 256){
        unsigned u = absbits(s[i]);
        bool keep;
        if (u > tb) keep = true;
        else if (u < tb) keep = false;
        else if (rem == 0u) keep = true;
        else {
            unsigned cnt = 0u;
            for (int e = 0; e < i; ++e) cnt += (absbits(s[e]) == tb) ? 1u : 0u;
            keep = (cnt >= rem);
        }
        float val = keep ? w[i] : 0.0f;
        int o = i / K, k = i % K;
        out[k*LD + o] = val;
    }
}

__global__ __launch_bounds__(256) void mask_kernel(
    const float* w1, const float* s1, float* o1,
    const float* w2, const float* s2, float* o2,
    const float* w3, const float* s3, float* o3,
    const float* w4, const float* s4, float* o4,
    const float* w5, const float* s5, float* o5)
{
    switch (blockIdx.x){
        case 0: mask_one<  150,    75,  25,   8>(s1, w1, o1); break; // conv1 -> [25][8] (oc padded)
        case 1: mask_one< 2400,  1200, 150,  16>(s2, w2, o2); break; // conv2 -> [150][16]
        case 2: mask_one<48000, 24000, 400, 120>(s3, w3, o3); break; // fc1   -> [400][120]
        case 3: mask_one<10080,  5040, 120,  84>(s4, w4, o4); break; // fc2   -> [120][84]
        case 4: mask_one<  840,   420,  84,  10>(s5, w5, o5); break; // fc3   -> [84][10]
    }
}

// ---------------------------------------------------------------------------
// conv1 (1->6, k5, pad1, 28->26) + BN + ReLU + maxpool2 -> [B,6,13,13]
// 2 images/block of 192 threads. Thread tile: 3 oc-pairs x 2convrow x 4convcol
// packed-fp32 accumulators (v_pk_fma_f32), row-rolled LDS reads.
// ---------------------------------------------------------------------------
__global__ __launch_bounds__(192) void conv1_kernel(
    const float* __restrict__ x, const float* __restrict__ wp,
    const float* __restrict__ b, const float* __restrict__ g,
    const float* __restrict__ be, const float* __restrict__ m,
    const float* __restrict__ v, float* __restrict__ out, int B)
{
    __shared__ float  t[2][30][33];
    __shared__ float4 w[25][2];          // [k][2xfloat4] : 6 oc used, 2 pad
    __shared__ float  sc[6], sf[6];
    const int tid  = threadIdx.x;
    const int img0 = blockIdx.x * 2;
    for (int i = tid; i < 2*30*33; i += 192) ((float*)t)[i] = 0.0f;
    if (tid < 50) ((float4*)w)[tid] = ((const float4*)wp)[tid];
    if (tid < 6){
        float inv = g[tid] / sqrtf(v[tid] + EPS);
        sc[tid] = inv; sf[tid] = (b[tid] - m[tid])*inv + be[tid];
    }
    __syncthreads();
    const int nimg = min(2, B - img0);
    for (int i = tid; i < nimg*784; i += 192){
        int im = i/784, p = i%784, r = p/28, c = p%28;
        t[im][r+1][c+1] = x[(size_t)(img0+im)*784 + p];
    }
    __syncthreads();
    if (tid < nimg*91){
        const int im = tid/91, tl = tid%91, py = tl/7, ct = tl%7;
        const int cy0 = 2*py, cx0 = 4*ct;
        v2f acc[3][2][4] = {};           // [ocpair][convrow][convcol]
        float rows[2][8];
        #pragma unroll
        for (int c = 0; c < 8; ++c){
            rows[0][c] = t[im][cy0  ][cx0+c];
            rows[1][c] = t[im][cy0+1][cx0+c];
        }
        #pragma unroll
        for (int ky = 0; ky < 5; ++ky){
            const int b0 = ky & 1, b1 = (ky+1) & 1;
            #pragma unroll
            for (int kx = 0; kx < 5; ++kx){
                const float4 wa = w[ky*5+kx][0];
                const float4 wb = w[ky*5+kx][1];
                const v2f w01 = {wa.x, wa.y};
                const v2f w23 = {wa.z, wa.w};
                const v2f w45 = {wb.x, wb.y};
                #pragma unroll
                for (int cx = 0; cx < 4; ++cx){
                    const v2f x0 = splat2(rows[b0][cx+kx]);
                    const v2f x1 = splat2(rows[b1][cx+kx]);
                    acc[0][0][cx] = pkfma(x0, w01, acc[0][0][cx]);
                    acc[1][0][cx] = pkfma(x0, w23, acc[1][0][cx]);
                    acc[2][0][cx] = pkfma(x0, w45, acc[2][0][cx]);
                    acc[0][1][cx] = pkfma(x1, w01, acc[0][1][cx]);
                    acc[1][1][cx] = pkfma(x1, w23, acc[1][1][cx]);
                    acc[2][1][cx] = pkfma(x1, w45, acc[2][1][cx]);
                }
            }
            if (ky < 4){
                #pragma unroll
                for (int c = 0; c < 8; ++c) rows[b0][c] = t[im][cy0+ky+2][cx0+c];
            }
        }
        const int gim = img0 + im;
        #pragma unroll
        for (int p = 0; p < 3; ++p){
            const v2f scv = {sc[2*p], sc[2*p+1]};
            const v2f sfv = {sf[2*p], sf[2*p+1]};
            #pragma unroll
            for (int px = 0; px < 2; ++px){
                const int pxg = 2*ct + px;
                if (pxg < 13){
                    const v2f v00 = pkfma(acc[p][0][2*px  ], scv, sfv);
                    const v2f v01 = pkfma(acc[p][0][2*px+1], scv, sfv);
                    const v2f v10 = pkfma(acc[p][1][2*px  ], scv, sfv);
                    const v2f v11 = pkfma(acc[p][1][2*px+1], scv, sfv);
                    const v2f mv  = pkmax(pkmax(v00, v01), pkmax(v10, v11));
                    out[((size_t)gim*6 + 2*p  )*169 + py*13 + pxg] = fmaxf(mv.x, 0.0f);
                    out[((size_t)gim*6 + 2*p+1)*169 + py*13 + pxg] = fmaxf(mv.y, 0.0f);
                }
            }
        }
    }
}

// ---------------------------------------------------------------------------
// conv2 (6->16, k5, pad1, 13->11) + BN + ReLU + maxpool2 -> [B,16,5,5]=[B,400]
// 6 images/block of 256 threads (240 active). Thread tile: 1 oc-pair x
// 2convrow x 10convcol packed-fp32 accumulators, row-rolled LDS reads.
// Input LDS [im][6][15][15]; weights LDS transposed [150][16].
// ---------------------------------------------------------------------------
#define C2_IM 6
__global__ __launch_bounds__(256) void conv2_kernel(
    const float* __restrict__ in, const float* __restrict__ wT,
    const float* __restrict__ b, const float* __restrict__ g,
    const float* __restrict__ be, const float* __restrict__ m,
    const float* __restrict__ v, float* __restrict__ out, int B)
{
    __shared__ float t[C2_IM][6][15][15];
    __shared__ float w[150][16];
    __shared__ float sc[16], sf[16];
    const int tid  = threadIdx.x;
    const int img0 = blockIdx.x * C2_IM;
    for (int i = tid; i < C2_IM*6*15*15; i += 256) ((float*)t)[i] = 0.0f;
    for (int i = tid; i < 2400; i += 256) ((float*)w)[i] = wT[i];
    if (tid < 16){
        float inv = g[tid] / sqrtf(v[tid] + EPS);
        sc[tid] = inv; sf[tid] = (b[tid] - m[tid])*inv + be[tid];
    }
    __syncthreads();
    const int nimg = min(C2_IM, B - img0);
    for (int i = tid; i < nimg*1014; i += 256){
        int im = i/1014, p = i%1014, ic = p/169, q = p%169, r = q/13, c = q%13;
        t[im][ic][r+1][c+1] = in[(size_t)(img0+im)*1014 + p];
    }
    __syncthreads();
    if (tid < nimg*40){
        const int im = tid/40, tl = tid%40, og = tl/5, cyp = tl%5;
        const int oc0 = og*2, cy0 = cyp*2;
        v2f acc[2][10] = {};             // [convrow][convcol], oc-pair in vector
        for (int ic = 0; ic < 6; ++ic){  // rolled: keeps I$ small
            float rows[2][14];
            #pragma unroll
            for (int c = 0; c < 14; ++c){
                rows[0][c] = t[im][ic][cy0  ][c];
                rows[1][c] = t[im][ic][cy0+1][c];
            }
            #pragma unroll
            for (int ky = 0; ky < 5; ++ky){
                const int b0 = ky & 1, b1 = (ky+1) & 1;
                #pragma unroll
                for (int kx = 0; kx < 5; ++kx){
                    const int k = (ic*5 + ky)*5 + kx;
                    const v2f wv = *(const v2f*)&w[k][oc0];
                    #pragma unroll
                    for (int cx = 0; cx < 10; ++cx){
                        acc[0][cx] = pkfma(splat2(rows[b0][cx+kx]), wv, acc[0][cx]);
                        acc[1][cx] = pkfma(splat2(rows[b1][cx+kx]), wv, acc[1][cx]);
                    }
                }
                if (ky < 4){
                    #pragma unroll
                    for (int c = 0; c < 14; ++c) rows[b0][c] = t[im][ic][cy0+ky+2][c];
                }
            }
        }
        const int gim = img0 + im;
        const v2f scv = {sc[oc0], sc[oc0+1]};
        const v2f sfv = {sf[oc0], sf[oc0+1]};
        #pragma unroll
        for (int px = 0; px < 5; ++px){
            const v2f v00 = pkfma(acc[0][2*px  ], scv, sfv);
            const v2f v01 = pkfma(acc[0][2*px+1], scv, sfv);
            const v2f v10 = pkfma(acc[1][2*px  ], scv, sfv);
            const v2f v11 = pkfma(acc[1][2*px+1], scv, sfv);
            const v2f mv  = pkmax(pkmax(v00, v01), pkmax(v10, v11));
            out[(size_t)gim*400 + (oc0  )*25 + cyp*5 + px] = fmaxf(mv.x, 0.0f);
            out[(size_t)gim*400 + (oc0+1)*25 + cyp*5 + px] = fmaxf(mv.y, 0.0f);
        }
    }
}

// ---------------------------------------------------------------------------
// fc1(400->120)+ReLU -> fc2(120->84)+ReLU -> fc3(84->10), fused.
// 32 images/block of 256 threads. Register tiles 4out x 4img; weights read
// as coalesced float4 from pre-transposed [K][O] layouts in ws (L2-resident).
// ---------------------------------------------------------------------------
__global__ __launch_bounds__(256) void fc_kernel(
    const float* __restrict__ in,
    const float* __restrict__ w3T, const float* __restrict__ b3,
    const float* __restrict__ w4T, const float* __restrict__ b4,
    const float* __restrict__ w5T, const float* __restrict__ b5,
    float* __restrict__ out, int B)
{
    __shared__ float xs[32][400];
    __shared__ float h1[32][120];
    __shared__ float h2[32][84];
    const int tid  = threadIdx.x;
    const int img0 = blockIdx.x * 32;
    const int avail = (B - img0) * 400;
    for (int i = tid; i < 32*400; i += 256)
        ((float*)xs)[i] = (i < avail) ? in[(size_t)img0*400 + i] : 0.0f;
    __syncthreads();

    // fc1: 30 outgroups x 8 imggroups = 240 threads
    if (tid < 240){
        const int og = tid % 30, ig = tid / 30;
        const int o0 = og*4, im0 = ig*4;
        float a[4][4] = {};
        #pragma unroll 2
        for (int k = 0; k < 400; ++k){
            const float4 wv = *(const float4*)&w3T[k*120 + o0];
            const float x0 = xs[im0+0][k], x1 = xs[im0+1][k];
            const float x2 = xs[im0+2][k], x3 = xs[im0+3][k];
            a[0][0] += wv.x*x0; a[0][1] += wv.x*x1; a[0][2] += wv.x*x2; a[0][3] += wv.x*x3;
            a[1][0] += wv.y*x0; a[1][1] += wv.y*x1; a[1][2] += wv.y*x2; a[1][3] += wv.y*x3;
            a[2][0] += wv.z*x0; a[2][1] += wv.z*x1; a[2][2] += wv.z*x2; a[2][3] += wv.z*x3;
            a[3][0] += wv.w*x0; a[3][1] += wv.w*x1; a[3][2] += wv.w*x2; a[3][3] += wv.w*x3;
        }
        const float4 bb = *(const float4*)&b3[o0];
        const float bj[4] = {bb.x, bb.y, bb.z, bb.w};
        #pragma unroll
        for (int j = 0; j < 4; ++j)
            #pragma unroll
            for (int i = 0; i < 4; ++i)
                h1[im0+i][o0+j] = fmaxf(a[j][i] + bj[j], 0.0f);
    }
    __syncthreads();

    // fc2: 21 outgroups x 8 imggroups = 168 threads
    if (tid < 168){
        const int og = tid % 21, ig = tid / 21;
        const int o0 = og*4, im0 = ig*4;
        float a[4][4] = {};
        #pragma unroll 2
        for (int k = 0; k < 120; ++k){
            const float4 wv = *(const float4*)&w4T[k*84 + o0];
            const float x0 = h1[im0+0][k], x1 = h1[im0+1][k];
            const float x2 = h1[im0+2][k], x3 = h1[im0+3][k];
            a[0][0] += wv.x*x0; a[0][1] += wv.x*x1; a[0][2] += wv.x*x2; a[0][3] += wv.x*x3;
            a[1][0] += wv.y*x0; a[1][1] += wv.y*x1; a[1][2] += wv.y*x2; a[1][3] += wv.y*x3;
            a[2][0] += wv.z*x0; a[2][1] += wv.z*x1; a[2][2] += wv.z*x2; a[2][3] += wv.z*x3;
            a[3][0] += wv.w*x0; a[3][1] += wv.w*x1; a[3][2] += wv.w*x2; a[3][3] += wv.w*x3;
        }
        const float4 bb = *(const float4*)&b4[o0];
        const float bj[4] = {bb.x, bb.y, bb.z, bb.w};
        #pragma unroll
        for (int j = 0; j < 4; ++j)
            #pragma unroll
            for (int i = 0; i < 4; ++i)
                h2[im0+i][o0+j] = fmaxf(a[j][i] + bj[j], 0.0f);
    }
    __syncthreads();

    // fc3: 10 outs x 8 imggroups = 80 threads
    if (tid < 80){
        const int o = tid % 10, ig = tid / 10;
        const int im0 = ig*4;
        float a[4] = {};
        for (int k = 0; k < 84; ++k){
            const float wv = w5T[k*10 + o];
            a[0] += wv*h2[im0+0][k];
            a[1] += wv*h2[im0+1][k];
            a[2] += wv*h2[im0+2][k];
            a[3] += wv*h2[im0+3][k];
        }
        const float bv = b5[o];
        #pragma unroll
        for (int i = 0; i < 4; ++i){
            const int gim = img0 + im0 + i;
            if (gim < B) out[(size_t)gim*10 + o] = a[i] + bv;
        }
    }
}

// ---------------------------------------------------------------------------
extern "C" void kernel_launch(void* const* d_in, const int* in_sizes, int n_in,
                              void* d_out, int out_size, void* d_ws, size_t ws_size,
                              hipStream_t stream)
{
    const float* x   = (const float*)d_in[0];
    const float* w1  = (const float*)d_in[1];
    const float* b1  = (const float*)d_in[2];
    const float* s1  = (const float*)d_in[3];
    const float* g1  = (const float*)d_in[4];
    const float* be1 = (const float*)d_in[5];
    const float* m1  = (const float*)d_in[6];
    const float* v1  = (const float*)d_in[7];
    const float* w2  = (const float*)d_in[8];
    const float* b2  = (const float*)d_in[9];
    const float* s2  = (const float*)d_in[10];
    const float* g2  = (const float*)d_in[11];
    const float* be2 = (const float*)d_in[12];
    const float* m2  = (const float*)d_in[13];
    const float* v2  = (const float*)d_in[14];
    const float* w3  = (const float*)d_in[15];
    const float* b3  = (const float*)d_in[16];
    const float* s3  = (const float*)d_in[17];
    const float* w4  = (const float*)d_in[18];
    const float* b4  = (const float*)d_in[19];
    const float* s4  = (const float*)d_in[20];
    const float* w5  = (const float*)d_in[21];
    const float* b5  = (const float*)d_in[22];
    const float* s5  = (const float*)d_in[23];

    const int B = in_sizes[0] / 784;

    float* ws   = (float*)d_ws;
    float* wm1  = ws;              // [25][8]   = 200
    float* wm2T = ws + 200;        // [150][16] = 2400
    float* wm3T = ws + 2600;       // [400][120]= 48000
    float* wm4T = ws + 50600;      // [120][84] = 10080
    float* wm5T = ws + 60680;      // [84][10]  = 840
    float* bufs = ws + 61520;      // chunk buffers: [Bc][1014] + [Bc][400]

    // Workspace-adaptive chunking (host-side only; deterministic in ws_size/B,
    // so the launch sequence is identical on every call -> graph-capture safe).
    const size_t avail_f = (ws_size / 4 > 61520) ? ws_size / 4 - 61520 : 0;
    int Bc = B;                                   // single pass if it fits
    if ((size_t)B * 1414 > avail_f){
        size_t c = avail_f / 1414;                // floats per image pair
        c = (c / 96) * 96;                        // multiple of 2,6,32 tiles
        if (c < 96) c = 96;                       // minimum sane chunk
        if (c > (size_t)B) c = B;
        Bc = (int)c;
    }

    mask_kernel<<<dim3(5), dim3(256), 0, stream>>>(
        w1, s1, wm1, w2, s2, wm2T, w3, s3, wm3T, w4, s4, wm4T, w5, s5, wm5T);

    for (int base = 0; base < B; base += Bc){
        const int n = (B - base < Bc) ? (B - base) : Bc;
        float* buf1 = bufs;                       // [n][6][13][13]
        float* buf2 = bufs + (size_t)Bc * 1014;   // [n][400]

        conv1_kernel<<<dim3((n+1)/2), dim3(192), 0, stream>>>(
            x + (size_t)base*784, wm1, b1, g1, be1, m1, v1, buf1, n);

        conv2_kernel<<<dim3((n+C2_IM-1)/C2_IM), dim3(256), 0, stream>>>(
            buf1, wm2T, b2, g2, be2, m2, v2, buf2, n);

        fc_kernel<<<dim3((n+31)/32), dim3(256), 0, stream>>>(
            buf2, wm3T, b3, wm4T, b4, wm5T, b5, (float*)d_out + (size_t)base*10, n);
    }
}

// Round 9
// 418.049 us; speedup vs baseline: 1.3398x; 1.3398x over previous
//
#include <hip/hip_runtime.h>

#define EPS 1e-5f

typedef float v2f __attribute__((ext_vector_type(2)));

__device__ __forceinline__ v2f splat2(float s){ v2f r; r.x = s; r.y = s; return r; }
__device__ __forceinline__ v2f pkfma(v2f a, v2f b, v2f c){ return __builtin_elementwise_fma(a, b, c); }
__device__ __forceinline__ v2f pkmax(v2f a, v2f b){ return __builtin_elementwise_max(a, b); }

__device__ __forceinline__ unsigned absbits(float x){
    return __float_as_uint(x) & 0x7fffffffu;
}

// ---------------------------------------------------------------------------
// Supermask v2: keep top-half of |scores| by stable ascending rank.
// Exact 4x8-bit radix-select; REGISTER-RESIDENT abs-bits (loaded once,
// statically indexed -> stays in VGPRs), 1024 threads/block, LDS histogram.
// Writes masked weights TRANSPOSED: out[(i%K)*LD + i/K].
// One block per tensor.
// ---------------------------------------------------------------------------
template<int N, int J, int K, int LD>
__device__ void mask_one(const float* __restrict__ s, const float* __restrict__ w,
                         float* __restrict__ out)
{
    constexpr int NT = 1024;
    constexpr int C  = (N + NT - 1) / NT;   // values per thread (<=47)
    __shared__ unsigned hist[256];
    __shared__ unsigned sh_pref, sh_want;
    const int tid = threadIdx.x;

    // Load abs-bits once; independent coalesced loads pipeline in-flight.
    unsigned u[C];
    #pragma unroll
    for (int j = 0; j < C; ++j){
        const int i = tid + j*NT;
        u[j] = (i < N) ? absbits(s[i]) : 0xFFFFFFFFu;   // pad value never used
    }

    if (tid == 0){ sh_pref = 0u; sh_want = (unsigned)J; }

    #pragma unroll
    for (int r = 0; r < 4; ++r){
        const int shift = 24 - 8*r;
        if (tid < 256) hist[tid] = 0u;
        __syncthreads();                      // covers init write + hist zero
        const unsigned pref = sh_pref;
        #pragma unroll
        for (int j = 0; j < C; ++j){
            const int i = tid + j*NT;
            if (i < N){
                const bool match = (r == 0) || ((u[j] >> (shift + 8)) == pref);
                if (match) atomicAdd(&hist[(u[j] >> shift) & 0xFFu], 1u);
            }
        }
        __syncthreads();
        if (tid == 0){
            unsigned want = sh_want, cum = 0u; int b = 0;
            for (; b < 256; ++b){ unsigned h = hist[b]; if (cum + h > want) break; cum += h; }
            sh_want = want - cum;
            sh_pref = (pref << 8) | (unsigned)b;
        }
        __syncthreads();
    }
    const unsigned tb  = sh_pref;   // abs-bits of element at sorted position J
    const unsigned rem = sh_want;   // #ties (lowest index first) to also drop

    #pragma unroll
    for (int j = 0; j < C; ++j){
        const int i = tid + j*NT;
        if (i < N){
            bool keep;
            if (u[j] > tb) keep = true;
            else if (u[j] < tb) keep = false;
            else if (rem == 0u) keep = true;
            else {                            // exact-tie path: ~never taken
                unsigned cnt = 0u;
                for (int e = 0; e < i; ++e) cnt += (absbits(s[e]) == tb) ? 1u : 0u;
                keep = (cnt >= rem);
            }
            const float val = keep ? w[i] : 0.0f;
            out[(i % K) * LD + (i / K)] = val;
        }
    }
}

__global__ __launch_bounds__(1024) void mask_kernel(
    const float* w1, const float* s1, float* o1,
    const float* w2, const float* s2, float* o2,
    const float* w3, const float* s3, float* o3,
    const float* w4, const float* s4, float* o4,
    const float* w5, const float* s5, float* o5)
{
    switch (blockIdx.x){
        case 0: mask_one<  150,    75,  25,   8>(s1, w1, o1); break; // conv1 -> [25][8] (oc padded)
        case 1: mask_one< 2400,  1200, 150,  16>(s2, w2, o2); break; // conv2 -> [150][16]
        case 2: mask_one<48000, 24000, 400, 120>(s3, w3, o3); break; // fc1   -> [400][120]
        case 3: mask_one<10080,  5040, 120,  84>(s4, w4, o4); break; // fc2   -> [120][84]
        case 4: mask_one<  840,   420,  84,  10>(s5, w5, o5); break; // fc3   -> [84][10]
    }
}

// ---------------------------------------------------------------------------
// conv1 (1->6, k5, pad1, 28->26) + BN + ReLU + maxpool2 -> [B,6,13,13]
// 2 images/block of 192 threads. Thread tile: 3 oc-pairs x 2convrow x 4convcol
// packed-fp32 accumulators (v_pk_fma_f32), row-rolled LDS reads.
// ---------------------------------------------------------------------------
__global__ __launch_bounds__(192) void conv1_kernel(
    const float* __restrict__ x, const float* __restrict__ wp,
    const float* __restrict__ b, const float* __restrict__ g,
    const float* __restrict__ be, const float* __restrict__ m,
    const float* __restrict__ v, float* __restrict__ out, int B)
{
    __shared__ float  t[2][30][33];
    __shared__ float4 w[25][2];          // [k][2xfloat4] : 6 oc used, 2 pad
    __shared__ float  sc[6], sf[6];
    const int tid  = threadIdx.x;
    const int img0 = blockIdx.x * 2;
    for (int i = tid; i < 2*30*33; i += 192) ((float*)t)[i] = 0.0f;
    if (tid < 50) ((float4*)w)[tid] = ((const float4*)wp)[tid];
    if (tid < 6){
        float inv = g[tid] / sqrtf(v[tid] + EPS);
        sc[tid] = inv; sf[tid] = (b[tid] - m[tid])*inv + be[tid];
    }
    __syncthreads();
    const int nimg = min(2, B - img0);
    for (int i = tid; i < nimg*784; i += 192){
        int im = i/784, p = i%784, r = p/28, c = p%28;
        t[im][r+1][c+1] = x[(size_t)(img0+im)*784 + p];
    }
    __syncthreads();
    if (tid < nimg*91){
        const int im = tid/91, tl = tid%91, py = tl/7, ct = tl%7;
        const int cy0 = 2*py, cx0 = 4*ct;
        v2f acc[3][2][4] = {};           // [ocpair][convrow][convcol]
        float rows[2][8];
        #pragma unroll
        for (int c = 0; c < 8; ++c){
            rows[0][c] = t[im][cy0  ][cx0+c];
            rows[1][c] = t[im][cy0+1][cx0+c];
        }
        #pragma unroll
        for (int ky = 0; ky < 5; ++ky){
            const int b0 = ky & 1, b1 = (ky+1) & 1;
            #pragma unroll
            for (int kx = 0; kx < 5; ++kx){
                const float4 wa = w[ky*5+kx][0];
                const float4 wb = w[ky*5+kx][1];
                const v2f w01 = {wa.x, wa.y};
                const v2f w23 = {wa.z, wa.w};
                const v2f w45 = {wb.x, wb.y};
                #pragma unroll
                for (int cx = 0; cx < 4; ++cx){
                    const v2f x0 = splat2(rows[b0][cx+kx]);
                    const v2f x1 = splat2(rows[b1][cx+kx]);
                    acc[0][0][cx] = pkfma(x0, w01, acc[0][0][cx]);
                    acc[1][0][cx] = pkfma(x0, w23, acc[1][0][cx]);
                    acc[2][0][cx] = pkfma(x0, w45, acc[2][0][cx]);
                    acc[0][1][cx] = pkfma(x1, w01, acc[0][1][cx]);
                    acc[1][1][cx] = pkfma(x1, w23, acc[1][1][cx]);
                    acc[2][1][cx] = pkfma(x1, w45, acc[2][1][cx]);
                }
            }
            if (ky < 4){
                #pragma unroll
                for (int c = 0; c < 8; ++c) rows[b0][c] = t[im][cy0+ky+2][cx0+c];
            }
        }
        const int gim = img0 + im;
        #pragma unroll
        for (int p = 0; p < 3; ++p){
            const v2f scv = {sc[2*p], sc[2*p+1]};
            const v2f sfv = {sf[2*p], sf[2*p+1]};
            #pragma unroll
            for (int px = 0; px < 2; ++px){
                const int pxg = 2*ct + px;
                if (pxg < 13){
                    const v2f v00 = pkfma(acc[p][0][2*px  ], scv, sfv);
                    const v2f v01 = pkfma(acc[p][0][2*px+1], scv, sfv);
                    const v2f v10 = pkfma(acc[p][1][2*px  ], scv, sfv);
                    const v2f v11 = pkfma(acc[p][1][2*px+1], scv, sfv);
                    const v2f mv  = pkmax(pkmax(v00, v01), pkmax(v10, v11));
                    out[((size_t)gim*6 + 2*p  )*169 + py*13 + pxg] = fmaxf(mv.x, 0.0f);
                    out[((size_t)gim*6 + 2*p+1)*169 + py*13 + pxg] = fmaxf(mv.y, 0.0f);
                }
            }
        }
    }
}

// ---------------------------------------------------------------------------
// conv2 (6->16, k5, pad1, 13->11) + BN + ReLU + maxpool2 -> [B,16,5,5]=[B,400]
// 6 images/block of 256 threads (240 active). Thread tile: 1 oc-pair x
// 2convrow x 10convcol packed-fp32 accumulators, row-rolled LDS reads.
// Input LDS [im][6][15][15]; weights LDS transposed [150][16].
// ---------------------------------------------------------------------------
#define C2_IM 6
__global__ __launch_bounds__(256) void conv2_kernel(
    const float* __restrict__ in, const float* __restrict__ wT,
    const float* __restrict__ b, const float* __restrict__ g,
    const float* __restrict__ be, const float* __restrict__ m,
    const float* __restrict__ v, float* __restrict__ out, int B)
{
    __shared__ float t[C2_IM][6][15][15];
    __shared__ float w[150][16];
    __shared__ float sc[16], sf[16];
    const int tid  = threadIdx.x;
    const int img0 = blockIdx.x * C2_IM;
    for (int i = tid; i < C2_IM*6*15*15; i += 256) ((float*)t)[i] = 0.0f;
    for (int i = tid; i < 2400; i += 256) ((float*)w)[i] = wT[i];
    if (tid < 16){
        float inv = g[tid] / sqrtf(v[tid] + EPS);
        sc[tid] = inv; sf[tid] = (b[tid] - m[tid])*inv + be[tid];
    }
    __syncthreads();
    const int nimg = min(C2_IM, B - img0);
    for (int i = tid; i < nimg*1014; i += 256){
        int im = i/1014, p = i%1014, ic = p/169, q = p%169, r = q/13, c = q%13;
        t[im][ic][r+1][c+1] = in[(size_t)(img0+im)*1014 + p];
    }
    __syncthreads();
    if (tid < nimg*40){
        const int im = tid/40, tl = tid%40, og = tl/5, cyp = tl%5;
        const int oc0 = og*2, cy0 = cyp*2;
        v2f acc[2][10] = {};             // [convrow][convcol], oc-pair in vector
        for (int ic = 0; ic < 6; ++ic){  // rolled: keeps I$ small
            float rows[2][14];
            #pragma unroll
            for (int c = 0; c < 14; ++c){
                rows[0][c] = t[im][ic][cy0  ][c];
                rows[1][c] = t[im][ic][cy0+1][c];
            }
            #pragma unroll
            for (int ky = 0; ky < 5; ++ky){
                const int b0 = ky & 1, b1 = (ky+1) & 1;
                #pragma unroll
                for (int kx = 0; kx < 5; ++kx){
                    const int k = (ic*5 + ky)*5 + kx;
                    const v2f wv = *(const v2f*)&w[k][oc0];
                    #pragma unroll
                    for (int cx = 0; cx < 10; ++cx){
                        acc[0][cx] = pkfma(splat2(rows[b0][cx+kx]), wv, acc[0][cx]);
                        acc[1][cx] = pkfma(splat2(rows[b1][cx+kx]), wv, acc[1][cx]);
                    }
                }
                if (ky < 4){
                    #pragma unroll
                    for (int c = 0; c < 14; ++c) rows[b0][c] = t[im][ic][cy0+ky+2][c];
                }
            }
        }
        const int gim = img0 + im;
        const v2f scv = {sc[oc0], sc[oc0+1]};
        const v2f sfv = {sf[oc0], sf[oc0+1]};
        #pragma unroll
        for (int px = 0; px < 5; ++px){
            const v2f v00 = pkfma(acc[0][2*px  ], scv, sfv);
            const v2f v01 = pkfma(acc[0][2*px+1], scv, sfv);
            const v2f v10 = pkfma(acc[1][2*px  ], scv, sfv);
            const v2f v11 = pkfma(acc[1][2*px+1], scv, sfv);
            const v2f mv  = pkmax(pkmax(v00, v01), pkmax(v10, v11));
            out[(size_t)gim*400 + (oc0  )*25 + cyp*5 + px] = fmaxf(mv.x, 0.0f);
            out[(size_t)gim*400 + (oc0+1)*25 + cyp*5 + px] = fmaxf(mv.y, 0.0f);
        }
    }
}

// ---------------------------------------------------------------------------
// fc1(400->120)+ReLU -> fc2(120->84)+ReLU -> fc3(84->10), fused.
// 32 images/block of 256 threads. Register tiles 4out x 4img; weights read
// as coalesced float4 from pre-transposed [K][O] layouts in ws (L2-resident).
// ---------------------------------------------------------------------------
__global__ __launch_bounds__(256) void fc_kernel(
    const float* __restrict__ in,
    const float* __restrict__ w3T, const float* __restrict__ b3,
    const float* __restrict__ w4T, const float* __restrict__ b4,
    const float* __restrict__ w5T, const float* __restrict__ b5,
    float* __restrict__ out, int B)
{
    __shared__ float xs[32][400];
    __shared__ float h1[32][120];
    __shared__ float h2[32][84];
    const int tid  = threadIdx.x;
    const int img0 = blockIdx.x * 32;
    const int avail = (B - img0) * 400;
    for (int i = tid; i < 32*400; i += 256)
        ((float*)xs)[i] = (i < avail) ? in[(size_t)img0*400 + i] : 0.0f;
    __syncthreads();

    // fc1: 30 outgroups x 8 imggroups = 240 threads
    if (tid < 240){
        const int og = tid % 30, ig = tid / 30;
        const int o0 = og*4, im0 = ig*4;
        float a[4][4] = {};
        #pragma unroll 2
        for (int k = 0; k < 400; ++k){
            const float4 wv = *(const float4*)&w3T[k*120 + o0];
            const float x0 = xs[im0+0][k], x1 = xs[im0+1][k];
            const float x2 = xs[im0+2][k], x3 = xs[im0+3][k];
            a[0][0] += wv.x*x0; a[0][1] += wv.x*x1; a[0][2] += wv.x*x2; a[0][3] += wv.x*x3;
            a[1][0] += wv.y*x0; a[1][1] += wv.y*x1; a[1][2] += wv.y*x2; a[1][3] += wv.y*x3;
            a[2][0] += wv.z*x0; a[2][1] += wv.z*x1; a[2][2] += wv.z*x2; a[2][3] += wv.z*x3;
            a[3][0] += wv.w*x0; a[3][1] += wv.w*x1; a[3][2] += wv.w*x2; a[3][3] += wv.w*x3;
        }
        const float4 bb = *(const float4*)&b3[o0];
        const float bj[4] = {bb.x, bb.y, bb.z, bb.w};
        #pragma unroll
        for (int j = 0; j < 4; ++j)
            #pragma unroll
            for (int i = 0; i < 4; ++i)
                h1[im0+i][o0+j] = fmaxf(a[j][i] + bj[j], 0.0f);
    }
    __syncthreads();

    // fc2: 21 outgroups x 8 imggroups = 168 threads
    if (tid < 168){
        const int og = tid % 21, ig = tid / 21;
        const int o0 = og*4, im0 = ig*4;
        float a[4][4] = {};
        #pragma unroll 2
        for (int k = 0; k < 120; ++k){
            const float4 wv = *(const float4*)&w4T[k*84 + o0];
            const float x0 = h1[im0+0][k], x1 = h1[im0+1][k];
            const float x2 = h1[im0+2][k], x3 = h1[im0+3][k];
            a[0][0] += wv.x*x0; a[0][1] += wv.x*x1; a[0][2] += wv.x*x2; a[0][3] += wv.x*x3;
            a[1][0] += wv.y*x0; a[1][1] += wv.y*x1; a[1][2] += wv.y*x2; a[1][3] += wv.y*x3;
            a[2][0] += wv.z*x0; a[2][1] += wv.z*x1; a[2][2] += wv.z*x2; a[2][3] += wv.z*x3;
            a[3][0] += wv.w*x0; a[3][1] += wv.w*x1; a[3][2] += wv.w*x2; a[3][3] += wv.w*x3;
        }
        const float4 bb = *(const float4*)&b4[o0];
        const float bj[4] = {bb.x, bb.y, bb.z, bb.w};
        #pragma unroll
        for (int j = 0; j < 4; ++j)
            #pragma unroll
            for (int i = 0; i < 4; ++i)
                h2[im0+i][o0+j] = fmaxf(a[j][i] + bj[j], 0.0f);
    }
    __syncthreads();

    // fc3: 10 outs x 8 imggroups = 80 threads
    if (tid < 80){
        const int o = tid % 10, ig = tid / 10;
        const int im0 = ig*4;
        float a[4] = {};
        for (int k = 0; k < 84; ++k){
            const float wv = w5T[k*10 + o];
            a[0] += wv*h2[im0+0][k];
            a[1] += wv*h2[im0+1][k];
            a[2] += wv*h2[im0+2][k];
            a[3] += wv*h2[im0+3][k];
        }
        const float bv = b5[o];
        #pragma unroll
        for (int i = 0; i < 4; ++i){
            const int gim = img0 + im0 + i;
            if (gim < B) out[(size_t)gim*10 + o] = a[i] + bv;
        }
    }
}

// ---------------------------------------------------------------------------
extern "C" void kernel_launch(void* const* d_in, const int* in_sizes, int n_in,
                              void* d_out, int out_size, void* d_ws, size_t ws_size,
                              hipStream_t stream)
{
    const float* x   = (const float*)d_in[0];
    const float* w1  = (const float*)d_in[1];
    const float* b1  = (const float*)d_in[2];
    const float* s1  = (const float*)d_in[3];
    const float* g1  = (const float*)d_in[4];
    const float* be1 = (const float*)d_in[5];
    const float* m1  = (const float*)d_in[6];
    const float* v1  = (const float*)d_in[7];
    const float* w2  = (const float*)d_in[8];
    const float* b2  = (const float*)d_in[9];
    const float* s2  = (const float*)d_in[10];
    const float* g2  = (const float*)d_in[11];
    const float* be2 = (const float*)d_in[12];
    const float* m2  = (const float*)d_in[13];
    const float* v2  = (const float*)d_in[14];
    const float* w3  = (const float*)d_in[15];
    const float* b3  = (const float*)d_in[16];
    const float* s3  = (const float*)d_in[17];
    const float* w4  = (const float*)d_in[18];
    const float* b4  = (const float*)d_in[19];
    const float* s4  = (const float*)d_in[20];
    const float* w5  = (const float*)d_in[21];
    const float* b5  = (const float*)d_in[22];
    const float* s5  = (const float*)d_in[23];

    const int B = in_sizes[0] / 784;

    float* ws   = (float*)d_ws;
    float* wm1  = ws;              // [25][8]   = 200
    float* wm2T = ws + 200;        // [150][16] = 2400
    float* wm3T = ws + 2600;       // [400][120]= 48000
    float* wm4T = ws + 50600;      // [120][84] = 10080
    float* wm5T = ws + 60680;      // [84][10]  = 840
    float* bufs = ws + 61520;      // chunk buffers: [Bc][1014] + [Bc][400]

    // Workspace-adaptive chunking (host-side only; deterministic in ws_size/B,
    // so the launch sequence is identical on every call -> graph-capture safe).
    const size_t avail_f = (ws_size / 4 > 61520) ? ws_size / 4 - 61520 : 0;
    int Bc = B;                                   // single pass if it fits
    if ((size_t)B * 1414 > avail_f){
        size_t c = avail_f / 1414;                // floats per image pair
        c = (c / 96) * 96;                        // multiple of 2,6,32 tiles
        if (c < 96) c = 96;                       // minimum sane chunk
        if (c > (size_t)B) c = B;
        Bc = (int)c;
    }

    mask_kernel<<<dim3(5), dim3(1024), 0, stream>>>(
        w1, s1, wm1, w2, s2, wm2T, w3, s3, wm3T, w4, s4, wm4T, w5, s5, wm5T);

    for (int base = 0; base < B; base += Bc){
        const int n = (B - base < Bc) ? (B - base) : Bc;
        float* buf1 = bufs;                       // [n][6][13][13]
        float* buf2 = bufs + (size_t)Bc * 1014;   // [n][400]

        conv1_kernel<<<dim3((n+1)/2), dim3(192), 0, stream>>>(
            x + (size_t)base*784, wm1, b1, g1, be1, m1, v1, buf1, n);

        conv2_kernel<<<dim3((n+C2_IM-1)/C2_IM), dim3(256), 0, stream>>>(
            buf1, wm2T, b2, g2, be2, m2, v2, buf2, n);

        fc_kernel<<<dim3((n+31)/32), dim3(256), 0, stream>>>(
            buf2, wm3T, b3, wm4T, b4, wm5T, b5, (float*)d_out + (size_t)base*10, n);
    }
}

// Round 13
// 415.846 us; speedup vs baseline: 1.3469x; 1.0053x over previous
//
#include <hip/hip_runtime.h>

#define EPS 1e-5f

typedef float v2f __attribute__((ext_vector_type(2)));

__device__ __forceinline__ v2f splat2(float s){ v2f r; r.x = s; r.y = s; return r; }
__device__ __forceinline__ v2f pkfma(v2f a, v2f b, v2f c){ return __builtin_elementwise_fma(a, b, c); }
__device__ __forceinline__ v2f pkmax(v2f a, v2f b){ return __builtin_elementwise_max(a, b); }

__device__ __forceinline__ unsigned absbits(float x){
    return __float_as_uint(x) & 0x7fffffffu;
}

// ---------------------------------------------------------------------------
// Supermask v3: keep top-half of |scores| by stable ascending rank.
// Exact 4x8-bit radix-select. Register-resident abs-bits; 16 per-wave
// sub-histograms (padded [16][257] -> bank-spread, 16x less atomic
// contention); wave-parallel bucket selection via __shfl_up scan (replaces
// the serial tid==0 256-bucket loop that dominated v2 at ~50us).
// Writes masked weights TRANSPOSED: out[(i%K)*LD + i/K]. One block/tensor.
// ---------------------------------------------------------------------------
template<int N, int J, int K, int LD>
__device__ void mask_one(const float* __restrict__ s, const float* __restrict__ w,
                         float* __restrict__ out)
{
    constexpr int NT = 1024;
    constexpr int C  = (N + NT - 1) / NT;   // values per thread (<=47)
    constexpr int NH = 16;                  // one sub-histogram per wave
    __shared__ unsigned hist[NH][257];      // 257: pad -> banks spread
    __shared__ unsigned sh_pref, sh_want;
    const int tid  = threadIdx.x;
    const int wid  = tid >> 6;
    const int lane = tid & 63;

    // Load abs-bits once; independent coalesced loads pipeline in-flight.
    unsigned u[C];
    #pragma unroll
    for (int j = 0; j < C; ++j){
        const int i = tid + j*NT;
        u[j] = (i < N) ? absbits(s[i]) : 0xFFFFFFFFu;   // pad never used
    }
    if (tid == 0){ sh_pref = 0u; sh_want = (unsigned)J; }

    #pragma unroll
    for (int r = 0; r < 4; ++r){
        const int shift = 24 - 8*r;
        for (int i2 = tid; i2 < NH*257; i2 += NT) ((unsigned*)hist)[i2] = 0u;
        __syncthreads();                    // covers init write + hist zero
        const unsigned pref = sh_pref;
        #pragma unroll
        for (int j = 0; j < C; ++j){
            const int i = tid + j*NT;
            if (i < N){
                const bool match = (r == 0) || ((u[j] >> (shift + 8)) == pref);
                if (match) atomicAdd(&hist[wid][(u[j] >> shift) & 0xFFu], 1u);
            }
        }
        __syncthreads();
        if (tid < 64){                      // wave 0: parallel selection
            const unsigned want = sh_want;
            unsigned s0=0, s1=0, s2=0, s3=0;   // 4 buckets per lane
            #pragma unroll
            for (int h = 0; h < NH; ++h){
                s0 += hist[h][4*tid+0];
                s1 += hist[h][4*tid+1];
                s2 += hist[h][4*tid+2];
                s3 += hist[h][4*tid+3];
            }
            const unsigned lsum = s0+s1+s2+s3;
            unsigned pre = lsum;            // inclusive scan over 64 lanes
            #pragma unroll
            for (int off = 1; off < 64; off <<= 1){
                const unsigned t = __shfl_up(pre, off);
                if (lane >= off) pre += t;
            }
            const unsigned c0 = pre - lsum; // exclusive prefix of bucket 4*tid
            const unsigned c1 = c0 + s0, c2 = c1 + s1, c3 = c2 + s2, c4 = c3 + s3;
            int b = -1; unsigned base = 0u;
            if      (want >= c0 && want < c1){ b = 4*tid+0; base = c0; }
            else if (want >= c1 && want < c2){ b = 4*tid+1; base = c1; }
            else if (want >= c2 && want < c3){ b = 4*tid+2; base = c2; }
            else if (want >= c3 && want < c4){ b = 4*tid+3; base = c3; }
            if (b >= 0){                    // exactly one lane hits
                sh_want = want - base;
                sh_pref = (pref << 8) | (unsigned)b;
            }
        }
        __syncthreads();
    }
    const unsigned tb  = sh_pref;   // abs-bits of element at sorted position J
    const unsigned rem = sh_want;   // #ties (lowest index first) to also drop

    #pragma unroll
    for (int j = 0; j < C; ++j){
        const int i = tid + j*NT;
        if (i < N){
            bool keep;
            if (u[j] > tb) keep = true;
            else if (u[j] < tb) keep = false;
            else if (rem == 0u) keep = true;
            else {                          // exact-tie path: ~never taken
                unsigned cnt = 0u;
                for (int e = 0; e < i; ++e) cnt += (absbits(s[e]) == tb) ? 1u : 0u;
                keep = (cnt >= rem);
            }
            const float val = keep ? w[i] : 0.0f;
            out[(i % K) * LD + (i / K)] = val;
        }
    }
}

__global__ __launch_bounds__(1024) void mask_kernel(
    const float* w1, const float* s1, float* o1,
    const float* w2, const float* s2, float* o2,
    const float* w3, const float* s3, float* o3,
    const float* w4, const float* s4, float* o4,
    const float* w5, const float* s5, float* o5)
{
    switch (blockIdx.x){
        case 0: mask_one<  150,    75,  25,   8>(s1, w1, o1); break; // conv1 -> [25][8] (oc padded)
        case 1: mask_one< 2400,  1200, 150,  16>(s2, w2, o2); break; // conv2 -> [150][16]
        case 2: mask_one<48000, 24000, 400, 120>(s3, w3, o3); break; // fc1   -> [400][120]
        case 3: mask_one<10080,  5040, 120,  84>(s4, w4, o4); break; // fc2   -> [120][84]
        case 4: mask_one<  840,   420,  84,  10>(s5, w5, o5); break; // fc3   -> [84][10]
    }
}

// ---------------------------------------------------------------------------
// conv1 (1->6, k5, pad1, 28->26) + BN + ReLU + maxpool2 -> [B,6,13,13]
// 2 images/block of 192 threads. Thread tile: 3 oc-pairs x 2convrow x 4convcol
// packed-fp32 accumulators (v_pk_fma_f32), row-rolled LDS reads.
// ---------------------------------------------------------------------------
__global__ __launch_bounds__(192) void conv1_kernel(
    const float* __restrict__ x, const float* __restrict__ wp,
    const float* __restrict__ b, const float* __restrict__ g,
    const float* __restrict__ be, const float* __restrict__ m,
    const float* __restrict__ v, float* __restrict__ out, int B)
{
    __shared__ float  t[2][30][33];
    __shared__ float4 w[25][2];          // [k][2xfloat4] : 6 oc used, 2 pad
    __shared__ float  sc[6], sf[6];
    const int tid  = threadIdx.x;
    const int img0 = blockIdx.x * 2;
    for (int i = tid; i < 2*30*33; i += 192) ((float*)t)[i] = 0.0f;
    if (tid < 50) ((float4*)w)[tid] = ((const float4*)wp)[tid];
    if (tid < 6){
        float inv = g[tid] / sqrtf(v[tid] + EPS);
        sc[tid] = inv; sf[tid] = (b[tid] - m[tid])*inv + be[tid];
    }
    __syncthreads();
    const int nimg = min(2, B - img0);
    for (int i = tid; i < nimg*784; i += 192){
        int im = i/784, p = i%784, r = p/28, c = p%28;
        t[im][r+1][c+1] = x[(size_t)(img0+im)*784 + p];
    }
    __syncthreads();
    if (tid < nimg*91){
        const int im = tid/91, tl = tid%91, py = tl/7, ct = tl%7;
        const int cy0 = 2*py, cx0 = 4*ct;
        v2f acc[3][2][4] = {};           // [ocpair][convrow][convcol]
        float rows[2][8];
        #pragma unroll
        for (int c = 0; c < 8; ++c){
            rows[0][c] = t[im][cy0  ][cx0+c];
            rows[1][c] = t[im][cy0+1][cx0+c];
        }
        #pragma unroll
        for (int ky = 0; ky < 5; ++ky){
            const int b0 = ky & 1, b1 = (ky+1) & 1;
            #pragma unroll
            for (int kx = 0; kx < 5; ++kx){
                const float4 wa = w[ky*5+kx][0];
                const float4 wb = w[ky*5+kx][1];
                const v2f w01 = {wa.x, wa.y};
                const v2f w23 = {wa.z, wa.w};
                const v2f w45 = {wb.x, wb.y};
                #pragma unroll
                for (int cx = 0; cx < 4; ++cx){
                    const v2f x0 = splat2(rows[b0][cx+kx]);
                    const v2f x1 = splat2(rows[b1][cx+kx]);
                    acc[0][0][cx] = pkfma(x0, w01, acc[0][0][cx]);
                    acc[1][0][cx] = pkfma(x0, w23, acc[1][0][cx]);
                    acc[2][0][cx] = pkfma(x0, w45, acc[2][0][cx]);
                    acc[0][1][cx] = pkfma(x1, w01, acc[0][1][cx]);
                    acc[1][1][cx] = pkfma(x1, w23, acc[1][1][cx]);
                    acc[2][1][cx] = pkfma(x1, w45, acc[2][1][cx]);
                }
            }
            if (ky < 4){
                #pragma unroll
                for (int c = 0; c < 8; ++c) rows[b0][c] = t[im][cy0+ky+2][cx0+c];
            }
        }
        const int gim = img0 + im;
        #pragma unroll
        for (int p = 0; p < 3; ++p){
            const v2f scv = {sc[2*p], sc[2*p+1]};
            const v2f sfv = {sf[2*p], sf[2*p+1]};
            #pragma unroll
            for (int px = 0; px < 2; ++px){
                const int pxg = 2*ct + px;
                if (pxg < 13){
                    const v2f v00 = pkfma(acc[p][0][2*px  ], scv, sfv);
                    const v2f v01 = pkfma(acc[p][0][2*px+1], scv, sfv);
                    const v2f v10 = pkfma(acc[p][1][2*px  ], scv, sfv);
                    const v2f v11 = pkfma(acc[p][1][2*px+1], scv, sfv);
                    const v2f mv  = pkmax(pkmax(v00, v01), pkmax(v10, v11));
                    out[((size_t)gim*6 + 2*p  )*169 + py*13 + pxg] = fmaxf(mv.x, 0.0f);
                    out[((size_t)gim*6 + 2*p+1)*169 + py*13 + pxg] = fmaxf(mv.y, 0.0f);
                }
            }
        }
    }
}

// ---------------------------------------------------------------------------
// conv2 (6->16, k5, pad1, 13->11) + BN + ReLU + maxpool2 -> [B,16,5,5]=[B,400]
// 6 images/block of 256 threads (240 active). Thread tile: 1 oc-pair x
// 2convrow x 10convcol packed-fp32 accumulators, row-rolled LDS reads.
// Input LDS [im][6][15][15]; weights LDS transposed [150][16].
// ---------------------------------------------------------------------------
#define C2_IM 6
__global__ __launch_bounds__(256) void conv2_kernel(
    const float* __restrict__ in, const float* __restrict__ wT,
    const float* __restrict__ b, const float* __restrict__ g,
    const float* __restrict__ be, const float* __restrict__ m,
    const float* __restrict__ v, float* __restrict__ out, int B)
{
    __shared__ float t[C2_IM][6][15][15];
    __shared__ float w[150][16];
    __shared__ float sc[16], sf[16];
    const int tid  = threadIdx.x;
    const int img0 = blockIdx.x * C2_IM;
    for (int i = tid; i < C2_IM*6*15*15; i += 256) ((float*)t)[i] = 0.0f;
    for (int i = tid; i < 2400; i += 256) ((float*)w)[i] = wT[i];
    if (tid < 16){
        float inv = g[tid] / sqrtf(v[tid] + EPS);
        sc[tid] = inv; sf[tid] = (b[tid] - m[tid])*inv + be[tid];
    }
    __syncthreads();
    const int nimg = min(C2_IM, B - img0);
    for (int i = tid; i < nimg*1014; i += 256){
        int im = i/1014, p = i%1014, ic = p/169, q = p%169, r = q/13, c = q%13;
        t[im][ic][r+1][c+1] = in[(size_t)(img0+im)*1014 + p];
    }
    __syncthreads();
    if (tid < nimg*40){
        const int im = tid/40, tl = tid%40, og = tl/5, cyp = tl%5;
        const int oc0 = og*2, cy0 = cyp*2;
        v2f acc[2][10] = {};             // [convrow][convcol], oc-pair in vector
        for (int ic = 0; ic < 6; ++ic){  // rolled: keeps I$ small
            float rows[2][14];
            #pragma unroll
            for (int c = 0; c < 14; ++c){
                rows[0][c] = t[im][ic][cy0  ][c];
                rows[1][c] = t[im][ic][cy0+1][c];
            }
            #pragma unroll
            for (int ky = 0; ky < 5; ++ky){
                const int b0 = ky & 1, b1 = (ky+1) & 1;
                #pragma unroll
                for (int kx = 0; kx < 5; ++kx){
                    const int k = (ic*5 + ky)*5 + kx;
                    const v2f wv = *(const v2f*)&w[k][oc0];
                    #pragma unroll
                    for (int cx = 0; cx < 10; ++cx){
                        acc[0][cx] = pkfma(splat2(rows[b0][cx+kx]), wv, acc[0][cx]);
                        acc[1][cx] = pkfma(splat2(rows[b1][cx+kx]), wv, acc[1][cx]);
                    }
                }
                if (ky < 4){
                    #pragma unroll
                    for (int c = 0; c < 14; ++c) rows[b0][c] = t[im][ic][cy0+ky+2][c];
                }
            }
        }
        const int gim = img0 + im;
        const v2f scv = {sc[oc0], sc[oc0+1]};
        const v2f sfv = {sf[oc0], sf[oc0+1]};
        #pragma unroll
        for (int px = 0; px < 5; ++px){
            const v2f v00 = pkfma(acc[0][2*px  ], scv, sfv);
            const v2f v01 = pkfma(acc[0][2*px+1], scv, sfv);
            const v2f v10 = pkfma(acc[1][2*px  ], scv, sfv);
            const v2f v11 = pkfma(acc[1][2*px+1], scv, sfv);
            const v2f mv  = pkmax(pkmax(v00, v01), pkmax(v10, v11));
            out[(size_t)gim*400 + (oc0  )*25 + cyp*5 + px] = fmaxf(mv.x, 0.0f);
            out[(size_t)gim*400 + (oc0+1)*25 + cyp*5 + px] = fmaxf(mv.y, 0.0f);
        }
    }
}

// ---------------------------------------------------------------------------
// fc1(400->120)+ReLU -> fc2(120->84)+ReLU -> fc3(84->10), fused.
// 32 images/block of 256 threads. Register tiles 4out x 4img; weights read
// as coalesced float4 from pre-transposed [K][O] layouts in ws (L2-resident).
// ---------------------------------------------------------------------------
__global__ __launch_bounds__(256) void fc_kernel(
    const float* __restrict__ in,
    const float* __restrict__ w3T, const float* __restrict__ b3,
    const float* __restrict__ w4T, const float* __restrict__ b4,
    const float* __restrict__ w5T, const float* __restrict__ b5,
    float* __restrict__ out, int B)
{
    __shared__ float xs[32][400];
    __shared__ float h1[32][120];
    __shared__ float h2[32][84];
    const int tid  = threadIdx.x;
    const int img0 = blockIdx.x * 32;
    const int avail = (B - img0) * 400;
    for (int i = tid; i < 32*400; i += 256)
        ((float*)xs)[i] = (i < avail) ? in[(size_t)img0*400 + i] : 0.0f;
    __syncthreads();

    // fc1: 30 outgroups x 8 imggroups = 240 threads
    if (tid < 240){
        const int og = tid % 30, ig = tid / 30;
        const int o0 = og*4, im0 = ig*4;
        float a[4][4] = {};
        #pragma unroll 2
        for (int k = 0; k < 400; ++k){
            const float4 wv = *(const float4*)&w3T[k*120 + o0];
            const float x0 = xs[im0+0][k], x1 = xs[im0+1][k];
            const float x2 = xs[im0+2][k], x3 = xs[im0+3][k];
            a[0][0] += wv.x*x0; a[0][1] += wv.x*x1; a[0][2] += wv.x*x2; a[0][3] += wv.x*x3;
            a[1][0] += wv.y*x0; a[1][1] += wv.y*x1; a[1][2] += wv.y*x2; a[1][3] += wv.y*x3;
            a[2][0] += wv.z*x0; a[2][1] += wv.z*x1; a[2][2] += wv.z*x2; a[2][3] += wv.z*x3;
            a[3][0] += wv.w*x0; a[3][1] += wv.w*x1; a[3][2] += wv.w*x2; a[3][3] += wv.w*x3;
        }
        const float4 bb = *(const float4*)&b3[o0];
        const float bj[4] = {bb.x, bb.y, bb.z, bb.w};
        #pragma unroll
        for (int j = 0; j < 4; ++j)
            #pragma unroll
            for (int i = 0; i < 4; ++i)
                h1[im0+i][o0+j] = fmaxf(a[j][i] + bj[j], 0.0f);
    }
    __syncthreads();

    // fc2: 21 outgroups x 8 imggroups = 168 threads
    if (tid < 168){
        const int og = tid % 21, ig = tid / 21;
        const int o0 = og*4, im0 = ig*4;
        float a[4][4] = {};
        #pragma unroll 2
        for (int k = 0; k < 120; ++k){
            const float4 wv = *(const float4*)&w4T[k*84 + o0];
            const float x0 = h1[im0+0][k], x1 = h1[im0+1][k];
            const float x2 = h1[im0+2][k], x3 = h1[im0+3][k];
            a[0][0] += wv.x*x0; a[0][1] += wv.x*x1; a[0][2] += wv.x*x2; a[0][3] += wv.x*x3;
            a[1][0] += wv.y*x0; a[1][1] += wv.y*x1; a[1][2] += wv.y*x2; a[1][3] += wv.y*x3;
            a[2][0] += wv.z*x0; a[2][1] += wv.z*x1; a[2][2] += wv.z*x2; a[2][3] += wv.z*x3;
            a[3][0] += wv.w*x0; a[3][1] += wv.w*x1; a[3][2] += wv.w*x2; a[3][3] += wv.w*x3;
        }
        const float4 bb = *(const float4*)&b4[o0];
        const float bj[4] = {bb.x, bb.y, bb.z, bb.w};
        #pragma unroll
        for (int j = 0; j < 4; ++j)
            #pragma unroll
            for (int i = 0; i < 4; ++i)
                h2[im0+i][o0+j] = fmaxf(a[j][i] + bj[j], 0.0f);
    }
    __syncthreads();

    // fc3: 10 outs x 8 imggroups = 80 threads
    if (tid < 80){
        const int o = tid % 10, ig = tid / 10;
        const int im0 = ig*4;
        float a[4] = {};
        for (int k = 0; k < 84; ++k){
            const float wv = w5T[k*10 + o];
            a[0] += wv*h2[im0+0][k];
            a[1] += wv*h2[im0+1][k];
            a[2] += wv*h2[im0+2][k];
            a[3] += wv*h2[im0+3][k];
        }
        const float bv = b5[o];
        #pragma unroll
        for (int i = 0; i < 4; ++i){
            const int gim = img0 + im0 + i;
            if (gim < B) out[(size_t)gim*10 + o] = a[i] + bv;
        }
    }
}

// ---------------------------------------------------------------------------
extern "C" void kernel_launch(void* const* d_in, const int* in_sizes, int n_in,
                              void* d_out, int out_size, void* d_ws, size_t ws_size,
                              hipStream_t stream)
{
    const float* x   = (const float*)d_in[0];
    const float* w1  = (const float*)d_in[1];
    const float* b1  = (const float*)d_in[2];
    const float* s1  = (const float*)d_in[3];
    const float* g1  = (const float*)d_in[4];
    const float* be1 = (const float*)d_in[5];
    const float* m1  = (const float*)d_in[6];
    const float* v1  = (const float*)d_in[7];
    const float* w2  = (const float*)d_in[8];
    const float* b2  = (const float*)d_in[9];
    const float* s2  = (const float*)d_in[10];
    const float* g2  = (const float*)d_in[11];
    const float* be2 = (const float*)d_in[12];
    const float* m2  = (const float*)d_in[13];
    const float* v2  = (const float*)d_in[14];
    const float* w3  = (const float*)d_in[15];
    const float* b3  = (const float*)d_in[16];
    const float* s3  = (const float*)d_in[17];
    const float* w4  = (const float*)d_in[18];
    const float* b4  = (const float*)d_in[19];
    const float* s4  = (const float*)d_in[20];
    const float* w5  = (const float*)d_in[21];
    const float* b5  = (const float*)d_in[22];
    const float* s5  = (const float*)d_in[23];

    const int B = in_sizes[0] / 784;

    float* ws   = (float*)d_ws;
    float* wm1  = ws;              // [25][8]   = 200
    float* wm2T = ws + 200;        // [150][16] = 2400
    float* wm3T = ws + 2600;       // [400][120]= 48000
    float* wm4T = ws + 50600;      // [120][84] = 10080
    float* wm5T = ws + 60680;      // [84][10]  = 840
    float* bufs = ws + 61520;      // chunk buffers: [Bc][1014] + [Bc][400]

    // Workspace-adaptive chunking (host-side only; deterministic in ws_size/B,
    // so the launch sequence is identical on every call -> graph-capture safe).
    const size_t avail_f = (ws_size / 4 > 61520) ? ws_size / 4 - 61520 : 0;
    int Bc = B;                                   // single pass if it fits
    if ((size_t)B * 1414 > avail_f){
        size_t c = avail_f / 1414;                // floats per image pair
        c = (c / 96) * 96;                        // multiple of 2,6,32 tiles
        if (c < 96) c = 96;                       // minimum sane chunk
        if (c > (size_t)B) c = B;
        Bc = (int)c;
    }

    mask_kernel<<<dim3(5), dim3(1024), 0, stream>>>(
        w1, s1, wm1, w2, s2, wm2T, w3, s3, wm3T, w4, s4, wm4T, w5, s5, wm5T);

    for (int base = 0; base < B; base += Bc){
        const int n = (B - base < Bc) ? (B - base) : Bc;
        float* buf1 = bufs;                       // [n][6][13][13]
        float* buf2 = bufs + (size_t)Bc * 1014;   // [n][400]

        conv1_kernel<<<dim3((n+1)/2), dim3(192), 0, stream>>>(
            x + (size_t)base*784, wm1, b1, g1, be1, m1, v1, buf1, n);

        conv2_kernel<<<dim3((n+C2_IM-1)/C2_IM), dim3(256), 0, stream>>>(
            buf1, wm2T, b2, g2, be2, m2, v2, buf2, n);

        fc_kernel<<<dim3((n+31)/32), dim3(256), 0, stream>>>(
            buf2, wm3T, b3, wm4T, b4, wm5T, b5, (float*)d_out + (size_t)base*10, n);
    }
}

// Round 14
// 413.764 us; speedup vs baseline: 1.3537x; 1.0050x over previous
//
#include <hip/hip_runtime.h>

#define EPS 1e-5f

typedef float v2f __attribute__((ext_vector_type(2)));

__device__ __forceinline__ v2f splat2(float s){ v2f r; r.x = s; r.y = s; return r; }
__device__ __forceinline__ v2f pkfma(v2f a, v2f b, v2f c){ return __builtin_elementwise_fma(a, b, c); }
__device__ __forceinline__ v2f pkmax(v2f a, v2f b){ return __builtin_elementwise_max(a, b); }

__device__ __forceinline__ unsigned absbits(float x){
    return __float_as_uint(x) & 0x7fffffffu;
}

// ---------------------------------------------------------------------------
// Supermask v4: keep top-half of |scores| by stable ascending rank.
// BITWISE RANK BISECTION (replaces radix histogram): build tb = sorted[J]
// bit-by-bit. Per step: count #(u < prefix|1<<b) from register-resident
// values (47 compares/thread), wave shfl-reduce, ONE atomicAdd per wave to a
// per-step counter, one barrier. No same-address atomic storms (v2/v3's
// 100us cost: skewed exponent buckets serialized ~48k LDS RMWs).
// Exact, stable-tie semantics: rem = J - cnt_less(tb).
// Writes masked weights TRANSPOSED: out[(i%K)*LD + i/K]. One block/tensor.
// ---------------------------------------------------------------------------
template<int N, int J, int K, int LD>
__device__ void mask_one(const float* __restrict__ s, const float* __restrict__ w,
                         float* __restrict__ out)
{
    constexpr int NT = 1024;
    constexpr int C  = (N + NT - 1) / NT;   // values per thread (<=47)
    __shared__ unsigned cnt[32];            // per-step counters (31 + rem pass)
    const int tid  = threadIdx.x;
    const int lane = tid & 63;

    // Load abs-bits once; independent coalesced loads pipeline in-flight.
    unsigned u[C];
    #pragma unroll
    for (int j = 0; j < C; ++j){
        const int i = tid + j*NT;
        u[j] = (i < N) ? absbits(s[i]) : 0xFFFFFFFFu;  // pad: never < T (T<=2^31)
    }
    if (tid < 32) cnt[tid] = 0u;
    __syncthreads();

    unsigned prefix = 0u;                   // sign bit always 0 -> bits 30..0
    for (int b = 30; b >= 0; --b){
        const unsigned T = prefix | (1u << b);
        unsigned c = 0u;
        #pragma unroll
        for (int j = 0; j < C; ++j) c += (u[j] < T) ? 1u : 0u;
        #pragma unroll
        for (int off = 32; off > 0; off >>= 1) c += __shfl_down(c, off);
        const int step = 30 - b;
        if (lane == 0) atomicAdd(&cnt[step], c);
        __syncthreads();
        if (cnt[step] <= (unsigned)J) prefix = T;   // uniform decision
    }
    const unsigned tb = prefix;             // abs-bits of sorted position J

    {   // rem = J - cnt_less(tb)
        unsigned c = 0u;
        #pragma unroll
        for (int j = 0; j < C; ++j) c += (u[j] < tb) ? 1u : 0u;
        #pragma unroll
        for (int off = 32; off > 0; off >>= 1) c += __shfl_down(c, off);
        if (lane == 0) atomicAdd(&cnt[31], c);
        __syncthreads();
    }
    const unsigned rem = (unsigned)J - cnt[31];  // #ties (lowest idx) to drop

    #pragma unroll
    for (int j = 0; j < C; ++j){
        const int i = tid + j*NT;
        if (i < N){
            bool keep;
            if (u[j] > tb) keep = true;
            else if (u[j] < tb) keep = false;
            else if (rem == 0u) keep = true;
            else {                          // exact-tie path: ~never taken
                unsigned cnt2 = 0u;
                for (int e = 0; e < i; ++e) cnt2 += (absbits(s[e]) == tb) ? 1u : 0u;
                keep = (cnt2 >= rem);
            }
            const float val = keep ? w[i] : 0.0f;
            out[(i % K) * LD + (i / K)] = val;
        }
    }
}

__global__ __launch_bounds__(1024) void mask_kernel(
    const float* w1, const float* s1, float* o1,
    const float* w2, const float* s2, float* o2,
    const float* w3, const float* s3, float* o3,
    const float* w4, const float* s4, float* o4,
    const float* w5, const float* s5, float* o5)
{
    switch (blockIdx.x){
        case 0: mask_one<  150,    75,  25,   8>(s1, w1, o1); break; // conv1 -> [25][8] (oc padded)
        case 1: mask_one< 2400,  1200, 150,  16>(s2, w2, o2); break; // conv2 -> [150][16]
        case 2: mask_one<48000, 24000, 400, 120>(s3, w3, o3); break; // fc1   -> [400][120]
        case 3: mask_one<10080,  5040, 120,  84>(s4, w4, o4); break; // fc2   -> [120][84]
        case 4: mask_one<  840,   420,  84,  10>(s5, w5, o5); break; // fc3   -> [84][10]
    }
}

// ---------------------------------------------------------------------------
// conv1 (1->6, k5, pad1, 28->26) + BN + ReLU + maxpool2 -> [B,6,13,13]
// 2 images/block of 192 threads. Thread tile: 3 oc-pairs x 2convrow x 4convcol
// packed-fp32 accumulators (v_pk_fma_f32), row-rolled LDS reads.
// ---------------------------------------------------------------------------
__global__ __launch_bounds__(192) void conv1_kernel(
    const float* __restrict__ x, const float* __restrict__ wp,
    const float* __restrict__ b, const float* __restrict__ g,
    const float* __restrict__ be, const float* __restrict__ m,
    const float* __restrict__ v, float* __restrict__ out, int B)
{
    __shared__ float  t[2][30][33];
    __shared__ float4 w[25][2];          // [k][2xfloat4] : 6 oc used, 2 pad
    __shared__ float  sc[6], sf[6];
    const int tid  = threadIdx.x;
    const int img0 = blockIdx.x * 2;
    for (int i = tid; i < 2*30*33; i += 192) ((float*)t)[i] = 0.0f;
    if (tid < 50) ((float4*)w)[tid] = ((const float4*)wp)[tid];
    if (tid < 6){
        float inv = g[tid] / sqrtf(v[tid] + EPS);
        sc[tid] = inv; sf[tid] = (b[tid] - m[tid])*inv + be[tid];
    }
    __syncthreads();
    const int nimg = min(2, B - img0);
    for (int i = tid; i < nimg*784; i += 192){
        int im = i/784, p = i%784, r = p/28, c = p%28;
        t[im][r+1][c+1] = x[(size_t)(img0+im)*784 + p];
    }
    __syncthreads();
    if (tid < nimg*91){
        const int im = tid/91, tl = tid%91, py = tl/7, ct = tl%7;
        const int cy0 = 2*py, cx0 = 4*ct;
        v2f acc[3][2][4] = {};           // [ocpair][convrow][convcol]
        float rows[2][8];
        #pragma unroll
        for (int c = 0; c < 8; ++c){
            rows[0][c] = t[im][cy0  ][cx0+c];
            rows[1][c] = t[im][cy0+1][cx0+c];
        }
        #pragma unroll
        for (int ky = 0; ky < 5; ++ky){
            const int b0 = ky & 1, b1 = (ky+1) & 1;
            #pragma unroll
            for (int kx = 0; kx < 5; ++kx){
                const float4 wa = w[ky*5+kx][0];
                const float4 wb = w[ky*5+kx][1];
                const v2f w01 = {wa.x, wa.y};
                const v2f w23 = {wa.z, wa.w};
                const v2f w45 = {wb.x, wb.y};
                #pragma unroll
                for (int cx = 0; cx < 4; ++cx){
                    const v2f x0 = splat2(rows[b0][cx+kx]);
                    const v2f x1 = splat2(rows[b1][cx+kx]);
                    acc[0][0][cx] = pkfma(x0, w01, acc[0][0][cx]);
                    acc[1][0][cx] = pkfma(x0, w23, acc[1][0][cx]);
                    acc[2][0][cx] = pkfma(x0, w45, acc[2][0][cx]);
                    acc[0][1][cx] = pkfma(x1, w01, acc[0][1][cx]);
                    acc[1][1][cx] = pkfma(x1, w23, acc[1][1][cx]);
                    acc[2][1][cx] = pkfma(x1, w45, acc[2][1][cx]);
                }
            }
            if (ky < 4){
                #pragma unroll
                for (int c = 0; c < 8; ++c) rows[b0][c] = t[im][cy0+ky+2][cx0+c];
            }
        }
        const int gim = img0 + im;
        #pragma unroll
        for (int p = 0; p < 3; ++p){
            const v2f scv = {sc[2*p], sc[2*p+1]};
            const v2f sfv = {sf[2*p], sf[2*p+1]};
            #pragma unroll
            for (int px = 0; px < 2; ++px){
                const int pxg = 2*ct + px;
                if (pxg < 13){
                    const v2f v00 = pkfma(acc[p][0][2*px  ], scv, sfv);
                    const v2f v01 = pkfma(acc[p][0][2*px+1], scv, sfv);
                    const v2f v10 = pkfma(acc[p][1][2*px  ], scv, sfv);
                    const v2f v11 = pkfma(acc[p][1][2*px+1], scv, sfv);
                    const v2f mv  = pkmax(pkmax(v00, v01), pkmax(v10, v11));
                    out[((size_t)gim*6 + 2*p  )*169 + py*13 + pxg] = fmaxf(mv.x, 0.0f);
                    out[((size_t)gim*6 + 2*p+1)*169 + py*13 + pxg] = fmaxf(mv.y, 0.0f);
                }
            }
        }
    }
}

// ---------------------------------------------------------------------------
// conv2 (6->16, k5, pad1, 13->11) + BN + ReLU + maxpool2 -> [B,16,5,5]=[B,400]
// 6 images/block of 256 threads (240 active). Thread tile: 1 oc-pair x
// 2convrow x 10convcol packed-fp32 accumulators, row-rolled LDS reads.
// Input LDS [im][6][15][15]; weights LDS transposed [150][16].
// ---------------------------------------------------------------------------
#define C2_IM 6
__global__ __launch_bounds__(256) void conv2_kernel(
    const float* __restrict__ in, const float* __restrict__ wT,
    const float* __restrict__ b, const float* __restrict__ g,
    const float* __restrict__ be, const float* __restrict__ m,
    const float* __restrict__ v, float* __restrict__ out, int B)
{
    __shared__ float t[C2_IM][6][15][15];
    __shared__ float w[150][16];
    __shared__ float sc[16], sf[16];
    const int tid  = threadIdx.x;
    const int img0 = blockIdx.x * C2_IM;
    for (int i = tid; i < C2_IM*6*15*15; i += 256) ((float*)t)[i] = 0.0f;
    for (int i = tid; i < 2400; i += 256) ((float*)w)[i] = wT[i];
    if (tid < 16){
        float inv = g[tid] / sqrtf(v[tid] + EPS);
        sc[tid] = inv; sf[tid] = (b[tid] - m[tid])*inv + be[tid];
    }
    __syncthreads();
    const int nimg = min(C2_IM, B - img0);
    for (int i = tid; i < nimg*1014; i += 256){
        int im = i/1014, p = i%1014, ic = p/169, q = p%169, r = q/13, c = q%13;
        t[im][ic][r+1][c+1] = in[(size_t)(img0+im)*1014 + p];
    }
    __syncthreads();
    if (tid < nimg*40){
        const int im = tid/40, tl = tid%40, og = tl/5, cyp = tl%5;
        const int oc0 = og*2, cy0 = cyp*2;
        v2f acc[2][10] = {};             // [convrow][convcol], oc-pair in vector
        for (int ic = 0; ic < 6; ++ic){  // rolled: keeps I$ small
            float rows[2][14];
            #pragma unroll
            for (int c = 0; c < 14; ++c){
                rows[0][c] = t[im][ic][cy0  ][c];
                rows[1][c] = t[im][ic][cy0+1][c];
            }
            #pragma unroll
            for (int ky = 0; ky < 5; ++ky){
                const int b0 = ky & 1, b1 = (ky+1) & 1;
                #pragma unroll
                for (int kx = 0; kx < 5; ++kx){
                    const int k = (ic*5 + ky)*5 + kx;
                    const v2f wv = *(const v2f*)&w[k][oc0];
                    #pragma unroll
                    for (int cx = 0; cx < 10; ++cx){
                        acc[0][cx] = pkfma(splat2(rows[b0][cx+kx]), wv, acc[0][cx]);
                        acc[1][cx] = pkfma(splat2(rows[b1][cx+kx]), wv, acc[1][cx]);
                    }
                }
                if (ky < 4){
                    #pragma unroll
                    for (int c = 0; c < 14; ++c) rows[b0][c] = t[im][ic][cy0+ky+2][c];
                }
            }
        }
        const int gim = img0 + im;
        const v2f scv = {sc[oc0], sc[oc0+1]};
        const v2f sfv = {sf[oc0], sf[oc0+1]};
        #pragma unroll
        for (int px = 0; px < 5; ++px){
            const v2f v00 = pkfma(acc[0][2*px  ], scv, sfv);
            const v2f v01 = pkfma(acc[0][2*px+1], scv, sfv);
            const v2f v10 = pkfma(acc[1][2*px  ], scv, sfv);
            const v2f v11 = pkfma(acc[1][2*px+1], scv, sfv);
            const v2f mv  = pkmax(pkmax(v00, v01), pkmax(v10, v11));
            out[(size_t)gim*400 + (oc0  )*25 + cyp*5 + px] = fmaxf(mv.x, 0.0f);
            out[(size_t)gim*400 + (oc0+1)*25 + cyp*5 + px] = fmaxf(mv.y, 0.0f);
        }
    }
}

// ---------------------------------------------------------------------------
// fc1(400->120)+ReLU -> fc2(120->84)+ReLU -> fc3(84->10), fused.
// 32 images/block of 256 threads. Register tiles 4out x 4img; weights read
// as coalesced float4 from pre-transposed [K][O] layouts in ws (L2-resident).
// ---------------------------------------------------------------------------
__global__ __launch_bounds__(256) void fc_kernel(
    const float* __restrict__ in,
    const float* __restrict__ w3T, const float* __restrict__ b3,
    const float* __restrict__ w4T, const float* __restrict__ b4,
    const float* __restrict__ w5T, const float* __restrict__ b5,
    float* __restrict__ out, int B)
{
    __shared__ float xs[32][400];
    __shared__ float h1[32][120];
    __shared__ float h2[32][84];
    const int tid  = threadIdx.x;
    const int img0 = blockIdx.x * 32;
    const int avail = (B - img0) * 400;
    for (int i = tid; i < 32*400; i += 256)
        ((float*)xs)[i] = (i < avail) ? in[(size_t)img0*400 + i] : 0.0f;
    __syncthreads();

    // fc1: 30 outgroups x 8 imggroups = 240 threads
    if (tid < 240){
        const int og = tid % 30, ig = tid / 30;
        const int o0 = og*4, im0 = ig*4;
        float a[4][4] = {};
        #pragma unroll 2
        for (int k = 0; k < 400; ++k){
            const float4 wv = *(const float4*)&w3T[k*120 + o0];
            const float x0 = xs[im0+0][k], x1 = xs[im0+1][k];
            const float x2 = xs[im0+2][k], x3 = xs[im0+3][k];
            a[0][0] += wv.x*x0; a[0][1] += wv.x*x1; a[0][2] += wv.x*x2; a[0][3] += wv.x*x3;
            a[1][0] += wv.y*x0; a[1][1] += wv.y*x1; a[1][2] += wv.y*x2; a[1][3] += wv.y*x3;
            a[2][0] += wv.z*x0; a[2][1] += wv.z*x1; a[2][2] += wv.z*x2; a[2][3] += wv.z*x3;
            a[3][0] += wv.w*x0; a[3][1] += wv.w*x1; a[3][2] += wv.w*x2; a[3][3] += wv.w*x3;
        }
        const float4 bb = *(const float4*)&b3[o0];
        const float bj[4] = {bb.x, bb.y, bb.z, bb.w};
        #pragma unroll
        for (int j = 0; j < 4; ++j)
            #pragma unroll
            for (int i = 0; i < 4; ++i)
                h1[im0+i][o0+j] = fmaxf(a[j][i] + bj[j], 0.0f);
    }
    __syncthreads();

    // fc2: 21 outgroups x 8 imggroups = 168 threads
    if (tid < 168){
        const int og = tid % 21, ig = tid / 21;
        const int o0 = og*4, im0 = ig*4;
        float a[4][4] = {};
        #pragma unroll 2
        for (int k = 0; k < 120; ++k){
            const float4 wv = *(const float4*)&w4T[k*84 + o0];
            const float x0 = h1[im0+0][k], x1 = h1[im0+1][k];
            const float x2 = h1[im0+2][k], x3 = h1[im0+3][k];
            a[0][0] += wv.x*x0; a[0][1] += wv.x*x1; a[0][2] += wv.x*x2; a[0][3] += wv.x*x3;
            a[1][0] += wv.y*x0; a[1][1] += wv.y*x1; a[1][2] += wv.y*x2; a[1][3] += wv.y*x3;
            a[2][0] += wv.z*x0; a[2][1] += wv.z*x1; a[2][2] += wv.z*x2; a[2][3] += wv.z*x3;
            a[3][0] += wv.w*x0; a[3][1] += wv.w*x1; a[3][2] += wv.w*x2; a[3][3] += wv.w*x3;
        }
        const float4 bb = *(const float4*)&b4[o0];
        const float bj[4] = {bb.x, bb.y, bb.z, bb.w};
        #pragma unroll
        for (int j = 0; j < 4; ++j)
            #pragma unroll
            for (int i = 0; i < 4; ++i)
                h2[im0+i][o0+j] = fmaxf(a[j][i] + bj[j], 0.0f);
    }
    __syncthreads();

    // fc3: 10 outs x 8 imggroups = 80 threads
    if (tid < 80){
        const int o = tid % 10, ig = tid / 10;
        const int im0 = ig*4;
        float a[4] = {};
        for (int k = 0; k < 84; ++k){
            const float wv = w5T[k*10 + o];
            a[0] += wv*h2[im0+0][k];
            a[1] += wv*h2[im0+1][k];
            a[2] += wv*h2[im0+2][k];
            a[3] += wv*h2[im0+3][k];
        }
        const float bv = b5[o];
        #pragma unroll
        for (int i = 0; i < 4; ++i){
            const int gim = img0 + im0 + i;
            if (gim < B) out[(size_t)gim*10 + o] = a[i] + bv;
        }
    }
}

// ---------------------------------------------------------------------------
extern "C" void kernel_launch(void* const* d_in, const int* in_sizes, int n_in,
                              void* d_out, int out_size, void* d_ws, size_t ws_size,
                              hipStream_t stream)
{
    const float* x   = (const float*)d_in[0];
    const float* w1  = (const float*)d_in[1];
    const float* b1  = (const float*)d_in[2];
    const float* s1  = (const float*)d_in[3];
    const float* g1  = (const float*)d_in[4];
    const float* be1 = (const float*)d_in[5];
    const float* m1  = (const float*)d_in[6];
    const float* v1  = (const float*)d_in[7];
    const float* w2  = (const float*)d_in[8];
    const float* b2  = (const float*)d_in[9];
    const float* s2  = (const float*)d_in[10];
    const float* g2  = (const float*)d_in[11];
    const float* be2 = (const float*)d_in[12];
    const float* m2  = (const float*)d_in[13];
    const float* v2  = (const float*)d_in[14];
    const float* w3  = (const float*)d_in[15];
    const float* b3  = (const float*)d_in[16];
    const float* s3  = (const float*)d_in[17];
    const float* w4  = (const float*)d_in[18];
    const float* b4  = (const float*)d_in[19];
    const float* s4  = (const float*)d_in[20];
    const float* w5  = (const float*)d_in[21];
    const float* b5  = (const float*)d_in[22];
    const float* s5  = (const float*)d_in[23];

    const int B = in_sizes[0] / 784;

    float* ws   = (float*)d_ws;
    float* wm1  = ws;              // [25][8]   = 200
    float* wm2T = ws + 200;        // [150][16] = 2400
    float* wm3T = ws + 2600;       // [400][120]= 48000
    float* wm4T = ws + 50600;      // [120][84] = 10080
    float* wm5T = ws + 60680;      // [84][10]  = 840
    float* bufs = ws + 61520;      // chunk buffers: [Bc][1014] + [Bc][400]

    // Workspace-adaptive chunking (host-side only; deterministic in ws_size/B,
    // so the launch sequence is identical on every call -> graph-capture safe).
    const size_t avail_f = (ws_size / 4 > 61520) ? ws_size / 4 - 61520 : 0;
    int Bc = B;                                   // single pass if it fits
    if ((size_t)B * 1414 > avail_f){
        size_t c = avail_f / 1414;                // floats per image pair
        c = (c / 96) * 96;                        // multiple of 2,6,32 tiles
        if (c < 96) c = 96;                       // minimum sane chunk
        if (c > (size_t)B) c = B;
        Bc = (int)c;
    }

    mask_kernel<<<dim3(5), dim3(1024), 0, stream>>>(
        w1, s1, wm1, w2, s2, wm2T, w3, s3, wm3T, w4, s4, wm4T, w5, s5, wm5T);

    for (int base = 0; base < B; base += Bc){
        const int n = (B - base < Bc) ? (B - base) : Bc;
        float* buf1 = bufs;                       // [n][6][13][13]
        float* buf2 = bufs + (size_t)Bc * 1014;   // [n][400]

        conv1_kernel<<<dim3((n+1)/2), dim3(192), 0, stream>>>(
            x + (size_t)base*784, wm1, b1, g1, be1, m1, v1, buf1, n);

        conv2_kernel<<<dim3((n+C2_IM-1)/C2_IM), dim3(256), 0, stream>>>(
            buf1, wm2T, b2, g2, be2, m2, v2, buf2, n);

        fc_kernel<<<dim3((n+31)/32), dim3(256), 0, stream>>>(
            buf2, wm3T, b3, wm4T, b4, wm5T, b5, (float*)d_out + (size_t)base*10, n);
    }
}